// Round 6
// baseline (339.084 us; speedup 1.0000x reference)
//
#include <hip/hip_runtime.h>

// Adaptive db4 wavelet transform, 5-level cascade, per-feature level select.
// B=32, S=4096, F=64, (b,s,f) f-contiguous, float4 lanes across f.
// lo_j[n] = sum_i h0[i]*lo_{j-1}[2n+i-3] (zero-extended), lengths 2048/1024/512/256/128.
//
// K1: level 1, n-QUAD per thread (14 tap loads -> 4 lo + 4 det outputs).
// K2: levels 2..5 fused, 128 blocks; block owns (b, 16-feature quarter) and the
//     full n-range of each level, so level j+1 reads back level j's global writes
//     after __syncthreads() (same CU -> visible). Writes lo2..lo5 (ws) + masked
//     det2..det5 heads (out).
// K3: pure streaming finalize: approx/low_freq via 4 uniform candidate loads +
//     per-component select, high_freq from det heads, all det zero tails.
//     Nontemporal stores throughout (nothing K3 writes is ever re-read).
//
// Output concat: approx[BSF] | det1..det5[5*BSF] | high_freq[BSF] | low_freq[BSF]

#define NB 32
#define NS 4096
#define NF 64
#define NF4 16
#define BSF (NB * NS * NF)

typedef float f4v __attribute__((ext_vector_type(4)));

__constant__ float c_h0[8] = {
     0.23037781330885523f,  0.7148465705525415f,   0.6308807679295904f,
    -0.02798376941698385f, -0.18703481171888114f,  0.030841381835986965f,
     0.032883011666982945f, -0.010597401784997278f};
__constant__ float c_h1[8] = {
    -0.010597401784997278f, -0.032883011666982945f, 0.030841381835986965f,
     0.18703481171888114f,  -0.02798376941698385f,  -0.6308807679295904f,
     0.7148465705525415f,   -0.23037781330885523f};

__device__ __forceinline__ void levels4(const float* __restrict__ scores, int f4,
                                        int lv[4]) {
    f4v s = ((const f4v*)scores)[f4];
#pragma unroll
    for (int c = 0; c < 4; ++c) {
        int l = 2 + (int)rintf(s[c] * 3.0f);   // round-half-even, matches jnp
        lv[c] = min(5, max(2, l));
    }
}

// K1: x (4096 rows) -> lo1 (2048 rows, ws) + det1 head (out). n-quad per thread.
__global__ __launch_bounds__(256) void wl_l1(
    const f4v* __restrict__ x, f4v* __restrict__ lo1, f4v* __restrict__ det1)
{
    int t = blockIdx.x * 256 + threadIdx.x;   // NB*512*NF4 threads
    int f4 = t & 15;
    int r = t >> 4;
    int nq = r & 511;
    int b  = r >> 9;
    int n0 = nq * 4;

    const f4v z = {0.f, 0.f, 0.f, 0.f};
    const f4v* row = x + (size_t)b * NS * NF4 + f4;
    f4v v[14];
    int base = 2 * n0 - 3;
#pragma unroll
    for (int j = 0; j < 14; ++j) {
        int m = base + j;
        v[j] = ((unsigned)m < (unsigned)NS) ? row[(size_t)m * NF4] : z;
    }
    f4v* lp = lo1  + (size_t)(b * 2048 + n0) * NF4 + f4;
    f4v* dp = det1 + (size_t)(b * NS   + n0) * NF4 + f4;
#pragma unroll
    for (int k = 0; k < 4; ++k) {
        f4v l = z, h = z;
#pragma unroll
        for (int i = 0; i < 8; ++i) { l += c_h0[i] * v[2*k + i]; h += c_h1[i] * v[2*k + i]; }
        lp[k * NF4] = l;
        dp[k * NF4] = h;
    }
}

// One level inside K2: src (TIN rows, global) -> lo (LEN rows) + det head (masked).
template <int TIN, int LEN, int J>
__device__ __forceinline__ void pyr_level(
    const f4v* __restrict__ src_base, f4v* __restrict__ lo_out,
    f4v* __restrict__ det, int b, int f4, int tn, const int lv[4])
{
    const f4v z = {0.f, 0.f, 0.f, 0.f};
    const f4v* src = src_base + (size_t)b * TIN * NF4 + f4;
#pragma unroll
    for (int k = 0; k < LEN / 64; ++k) {
        int n = tn + 64 * k;
        f4v l = z, h = z;
        int base = 2 * n - 3;
#pragma unroll
        for (int i = 0; i < 8; ++i) {
            int m = base + i;
            if ((unsigned)m < (unsigned)TIN) {
                f4v vv = src[(size_t)m * NF4];
                l += c_h0[i] * vv;  h += c_h1[i] * vv;
            }
        }
        if (J >= 3) {
#pragma unroll
            for (int c = 0; c < 4; ++c) if (lv[c] < J) h[c] = 0.f;
        }
        lo_out[(size_t)(b * LEN + n) * NF4 + f4] = l;
        det[(size_t)(b * NS + n) * NF4 + f4] = h;
    }
}

// K2: levels 2..5. Block = (b, f4-quarter). 128 blocks x 256 threads.
__global__ __launch_bounds__(256) void wl_pyr(
    const f4v* __restrict__ lo1, f4v* __restrict__ lo2, f4v* __restrict__ lo3,
    f4v* __restrict__ lo4, f4v* __restrict__ lo5,
    f4v* __restrict__ det2, f4v* __restrict__ det3, f4v* __restrict__ det4,
    f4v* __restrict__ det5, const float* __restrict__ scores)
{
    int b  = blockIdx.x >> 2;
    int q  = blockIdx.x & 3;
    int fl = threadIdx.x & 3;
    int tn = threadIdx.x >> 2;       // 0..63
    int f4 = q * 4 + fl;
    int lv[4];
    levels4(scores, f4, lv);

    pyr_level<2048, 1024, 2>(lo1, lo2, det2, b, f4, tn, lv);
    __syncthreads();                 // waits vmcnt(0): lo2 visible to this block
    pyr_level<1024,  512, 3>(lo2, lo3, det3, b, f4, tn, lv);
    __syncthreads();
    pyr_level< 512,  256, 4>(lo3, lo4, det4, b, f4, tn, lv);
    __syncthreads();
    pyr_level< 256,  128, 5>(lo4, lo5, det5, b, f4, tn, lv);
}

// K3: streaming finalize (full grid).
__global__ __launch_bounds__(256) void wl_out(
    const f4v* __restrict__ lo2, const f4v* __restrict__ lo3,
    const f4v* __restrict__ lo4, const f4v* __restrict__ lo5,
    f4v* __restrict__ out4, const float* __restrict__ scores)
{
    int t = blockIdx.x * 256 + threadIdx.x;   // BSF/4 threads
    int f4 = t & 15;
    int r = t >> 4;
    int n = r & (NS - 1);
    int b = r >> 12;
    int lv[4];
    levels4(scores, f4, lv);

    const f4v z = {0.f, 0.f, 0.f, 0.f};
    f4v* det1 = out4 + (size_t)1 * (BSF / 4);
    f4v* det2 = out4 + (size_t)2 * (BSF / 4);
    f4v* det3 = out4 + (size_t)3 * (BSF / 4);
    f4v* det4 = out4 + (size_t)4 * (BSF / 4);
    f4v* det5 = out4 + (size_t)5 * (BSF / 4);

    // approx candidates (bound conditions are wave-uniform; zero past each length)
    f4v c2 = (n < 1024) ? lo2[(size_t)(b * 1024 + n) * NF4 + f4] : z;
    f4v c3 = (n <  512) ? lo3[(size_t)(b *  512 + n) * NF4 + f4] : z;
    f4v c4 = (n <  256) ? lo4[(size_t)(b *  256 + n) * NF4 + f4] : z;
    f4v c5 = (n <  128) ? lo5[(size_t)(b *  128 + n) * NF4 + f4] : z;

    f4v av;
#pragma unroll
    for (int c = 0; c < 4; ++c)
        av[c] = (lv[c] == 2) ? c2[c] : (lv[c] == 3) ? c3[c]
              : (lv[c] == 4) ? c4[c] : c5[c];

    // high_freq = sum of masked det heads (det3..det5 stored pre-masked)
    f4v acc = z;
    if (n < 2048) acc += det1[t];
    if (n < 1024) acc += det2[t];
    if (n <  512) acc += det3[t];
    if (n <  256) acc += det4[t];
    if (n <  128) acc += det5[t];

    __builtin_nontemporal_store(av,  out4 + t);                          // approx
    __builtin_nontemporal_store(acc, out4 + (size_t)6 * (BSF / 4) + t);  // high_freq
    __builtin_nontemporal_store(av,  out4 + (size_t)7 * (BSF / 4) + t);  // low_freq
    if (n >= 2048) __builtin_nontemporal_store(z, det1 + t);             // zero tails
    if (n >= 1024) __builtin_nontemporal_store(z, det2 + t);
    if (n >=  512) __builtin_nontemporal_store(z, det3 + t);
    if (n >=  256) __builtin_nontemporal_store(z, det4 + t);
    if (n >=  128) __builtin_nontemporal_store(z, det5 + t);
}

extern "C" void kernel_launch(void* const* d_in, const int* in_sizes, int n_in,
                              void* d_out, int out_size, void* d_ws, size_t ws_size,
                              hipStream_t stream)
{
    const f4v* x        = (const f4v*)d_in[0];
    const float* scores = (const float*)d_in[1];
    f4v* out4 = (f4v*)d_out;

    // ws pyramid: lo1(2048) lo2(1024) lo3(512) lo4(256) lo5(128) rows -> 31 MiB
    f4v* lo1 = (f4v*)d_ws;
    f4v* lo2 = lo1 + (size_t)NB * 2048 * NF4;
    f4v* lo3 = lo2 + (size_t)NB * 1024 * NF4;
    f4v* lo4 = lo3 + (size_t)NB *  512 * NF4;
    f4v* lo5 = lo4 + (size_t)NB *  256 * NF4;

    f4v* det1 = out4 + (size_t)1 * (BSF / 4);
    f4v* det2 = out4 + (size_t)2 * (BSF / 4);
    f4v* det3 = out4 + (size_t)3 * (BSF / 4);
    f4v* det4 = out4 + (size_t)4 * (BSF / 4);
    f4v* det5 = out4 + (size_t)5 * (BSF / 4);

    dim3 block(256);
    wl_l1 <<<dim3(NB * 512 * NF4 / 256), block, 0, stream>>>(x, lo1, det1);
    wl_pyr<<<dim3(NB * 4),              block, 0, stream>>>(lo1, lo2, lo3, lo4, lo5,
                                                            det2, det3, det4, det5, scores);
    wl_out<<<dim3(BSF / 4 / 256),       block, 0, stream>>>(lo2, lo3, lo4, lo5,
                                                            out4, scores);
}

// Round 7
// 310.304 us; speedup vs baseline: 1.0927x; 1.0927x over previous
//
#include <hip/hip_runtime.h>

// Adaptive db4 wavelet transform, 5-level cascade, per-feature level select.
// B=32, S=4096, F=64, (b,s,f) f-contiguous, float4 lanes across f.
// lo_j[n] = sum_i h0[i]*lo_{j-1}[2n+i-3] (zero-extended), lengths 2048/1024/512/256/128.
//
// Structure (R5 five-kernel layout — fused pyramid regressed in R6):
//  K1: level 1, n-QUAD per thread (14 tap loads -> 4 lo + 4 det outputs).
//  K2..K4: levels 2..4, work-sized grids, n-PAIR per thread (10 loads / 2 outputs),
//          write lo head (ws) + masked det head (out).
//  K5: finalize (full grid): inline level-5 conv (n<128), det5, high_freq from det
//      heads + register d5, approx/low_freq via 3 uniform candidate loads + select,
//      all det zero tails. Nontemporal stores (nothing K5 writes is re-read).
//
// Output concat: approx[BSF] | det1..det5[5*BSF] | high_freq[BSF] | low_freq[BSF]

#define NB 32
#define NS 4096
#define NF 64
#define NF4 16
#define BSF (NB * NS * NF)

typedef float f4v __attribute__((ext_vector_type(4)));

__constant__ float c_h0[8] = {
     0.23037781330885523f,  0.7148465705525415f,   0.6308807679295904f,
    -0.02798376941698385f, -0.18703481171888114f,  0.030841381835986965f,
     0.032883011666982945f, -0.010597401784997278f};
__constant__ float c_h1[8] = {
    -0.010597401784997278f, -0.032883011666982945f, 0.030841381835986965f,
     0.18703481171888114f,  -0.02798376941698385f,  -0.6308807679295904f,
     0.7148465705525415f,   -0.23037781330885523f};

__device__ __forceinline__ void levels4(const float* __restrict__ scores, int f4,
                                        int lv[4]) {
    f4v s = ((const f4v*)scores)[f4];
#pragma unroll
    for (int c = 0; c < 4; ++c) {
        int l = 2 + (int)rintf(s[c] * 3.0f);   // round-half-even, matches jnp
        lv[c] = min(5, max(2, l));
    }
}

// K1: x (4096 rows) -> lo1 (2048 rows, ws) + det1 head (out). n-quad per thread.
__global__ __launch_bounds__(256) void wl_l1(
    const f4v* __restrict__ x, f4v* __restrict__ lo1, f4v* __restrict__ det1)
{
    int t = blockIdx.x * 256 + threadIdx.x;   // NB*512*NF4 threads
    int f4 = t & 15;
    int r = t >> 4;
    int nq = r & 511;
    int b  = r >> 9;
    int n0 = nq * 4;

    const f4v z = {0.f, 0.f, 0.f, 0.f};
    const f4v* row = x + (size_t)b * NS * NF4 + f4;
    f4v v[14];
    int base = 2 * n0 - 3;
#pragma unroll
    for (int j = 0; j < 14; ++j) {
        int m = base + j;
        v[j] = ((unsigned)m < (unsigned)NS) ? row[(size_t)m * NF4] : z;
    }
    f4v* lp = lo1  + (size_t)(b * 2048 + n0) * NF4 + f4;
    f4v* dp = det1 + (size_t)(b * NS   + n0) * NF4 + f4;
#pragma unroll
    for (int k = 0; k < 4; ++k) {
        f4v l = z, h = z;
#pragma unroll
        for (int i = 0; i < 8; ++i) { l += c_h0[i] * v[2*k + i]; h += c_h1[i] * v[2*k + i]; }
        lp[k * NF4] = l;
        dp[k * NF4] = h;
    }
}

// Levels 2..4: in (TIN rows) -> lo head (LEN rows, ws) + masked det head (out).
// Each thread owns the n-pair (2np, 2np+1): 10 tap rows cover both 8-tap windows.
template <int J, int TIN, int LOG2LEN>
__global__ __launch_bounds__(256) void wl_lvl(
    const f4v* __restrict__ in, f4v* __restrict__ lo_out,
    f4v* __restrict__ det, const float* __restrict__ scores)
{
    constexpr int LEN = 1 << LOG2LEN;
    int t = blockIdx.x * 256 + threadIdx.x;       // grid = NB*(LEN/2)*NF4 threads
    int f4 = t & (NF4 - 1);
    int r = t >> 4;
    int np = r & (LEN / 2 - 1);
    int b = r >> (LOG2LEN - 1);
    int n0 = 2 * np;

    const f4v* row = in + (size_t)b * TIN * NF4 + f4;
    const f4v z = {0.f, 0.f, 0.f, 0.f};
    f4v v[10];
    int base = n0 * 2 - 3;
#pragma unroll
    for (int j = 0; j < 10; ++j) {
        int m = base + j;
        v[j] = ((unsigned)m < (unsigned)TIN) ? row[(size_t)m * NF4] : z;
    }
    f4v lo0 = z, hi0 = z, lo1 = z, hi1 = z;
#pragma unroll
    for (int i = 0; i < 8; ++i) {
        lo0 += c_h0[i] * v[i];      hi0 += c_h1[i] * v[i];
        lo1 += c_h0[i] * v[i + 2];  hi1 += c_h1[i] * v[i + 2];
    }
    if (J >= 3) {                                  // det_J kept iff lv[f] >= J
        int lv[4];
        levels4(scores, f4, lv);
#pragma unroll
        for (int c = 0; c < 4; ++c)
            if (lv[c] < J) { hi0[c] = 0.f; hi1[c] = 0.f; }
    }
    f4v* lp = lo_out + (size_t)(b * LEN + n0) * NF4 + f4;
    lp[0] = lo0;  lp[NF4] = lo1;
    f4v* dp = det + (size_t)(b * NS + n0) * NF4 + f4;
    dp[0] = hi0;  dp[NF4] = hi1;
}

// K5: finalize (full grid). Inline level-5, high_freq, approx/low_freq, det tails.
__global__ __launch_bounds__(256) void wl_final(
    const f4v* __restrict__ lo2, const f4v* __restrict__ lo3,
    const f4v* __restrict__ lo4, f4v* __restrict__ out4,
    const float* __restrict__ scores)
{
    int t = blockIdx.x * 256 + threadIdx.x;        // BSF/4 threads
    int f4 = t & 15;
    int r = t >> 4;
    int n = r & (NS - 1);
    int b = r >> 12;
    int lv[4];
    levels4(scores, f4, lv);

    const f4v z = {0.f, 0.f, 0.f, 0.f};
    f4v d5 = z, l5 = z;
    if (n < 128) {                                 // level-5 conv over lo4 (256 rows)
        const f4v* row = lo4 + (size_t)b * 256 * NF4 + f4;
        int base = 2 * n - 3;
        f4v hi = z;
#pragma unroll
        for (int i = 0; i < 8; ++i) {
            int m = base + i;
            if ((unsigned)m < 256u) {
                f4v vv = row[(size_t)m * NF4];
                l5 += c_h0[i] * vv;  hi += c_h1[i] * vv;
            }
        }
#pragma unroll
        for (int c = 0; c < 4; ++c) d5[c] = (lv[c] >= 5) ? hi[c] : 0.f;
    }

    f4v* det1 = out4 + (size_t)1 * (BSF / 4);
    f4v* det2 = out4 + (size_t)2 * (BSF / 4);
    f4v* det3 = out4 + (size_t)3 * (BSF / 4);
    f4v* det4 = out4 + (size_t)4 * (BSF / 4);

    // approx candidates: wave-uniform bound checks, zero past each level length;
    // l5 is this thread's own register (zero for n >= 128).
    f4v c2 = (n < 1024) ? lo2[(size_t)(b * 1024 + n) * NF4 + f4] : z;
    f4v c3 = (n <  512) ? lo3[(size_t)(b *  512 + n) * NF4 + f4] : z;
    f4v c4 = (n <  256) ? lo4[(size_t)(b *  256 + n) * NF4 + f4] : z;
    f4v av;
#pragma unroll
    for (int c = 0; c < 4; ++c)
        av[c] = (lv[c] == 2) ? c2[c] : (lv[c] == 3) ? c3[c]
              : (lv[c] == 4) ? c4[c] : l5[c];

    // high_freq = sum of masked det heads + register d5
    f4v acc = d5;
    if (n < 2048) acc += det1[t];
    if (n < 1024) acc += det2[t];
    if (n <  512) acc += det3[t];
    if (n <  256) acc += det4[t];

    __builtin_nontemporal_store(av,  out4 + t);                          // approx
    __builtin_nontemporal_store(d5,  out4 + (size_t)5 * (BSF / 4) + t);  // det5
    __builtin_nontemporal_store(acc, out4 + (size_t)6 * (BSF / 4) + t);  // high_freq
    __builtin_nontemporal_store(av,  out4 + (size_t)7 * (BSF / 4) + t);  // low_freq
    if (n >= 2048) __builtin_nontemporal_store(z, det1 + t);             // zero tails
    if (n >= 1024) __builtin_nontemporal_store(z, det2 + t);
    if (n >=  512) __builtin_nontemporal_store(z, det3 + t);
    if (n >=  256) __builtin_nontemporal_store(z, det4 + t);
}

extern "C" void kernel_launch(void* const* d_in, const int* in_sizes, int n_in,
                              void* d_out, int out_size, void* d_ws, size_t ws_size,
                              hipStream_t stream)
{
    const f4v* x        = (const f4v*)d_in[0];
    const float* scores = (const float*)d_in[1];
    f4v* out4 = (f4v*)d_out;

    // ws pyramid: lo1(2048) lo2(1024) lo3(512) lo4(256) rows -> 30 MiB
    f4v* lo1 = (f4v*)d_ws;
    f4v* lo2 = lo1 + (size_t)NB * 2048 * NF4;
    f4v* lo3 = lo2 + (size_t)NB * 1024 * NF4;
    f4v* lo4 = lo3 + (size_t)NB *  512 * NF4;

    f4v* det1 = out4 + (size_t)1 * (BSF / 4);
    f4v* det2 = out4 + (size_t)2 * (BSF / 4);
    f4v* det3 = out4 + (size_t)3 * (BSF / 4);
    f4v* det4 = out4 + (size_t)4 * (BSF / 4);

    dim3 block(256);
    wl_l1<<<dim3(NB * 512 * NF4 / 256), block, 0, stream>>>(x, lo1, det1);
    wl_lvl<2, 2048, 10><<<dim3(NB * 512 * NF4 / 256), block, 0, stream>>>(lo1, lo2, det2, scores);
    wl_lvl<3, 1024,  9><<<dim3(NB * 256 * NF4 / 256), block, 0, stream>>>(lo2, lo3, det3, scores);
    wl_lvl<4,  512,  8><<<dim3(NB * 128 * NF4 / 256), block, 0, stream>>>(lo3, lo4, det4, scores);
    wl_final<<<dim3(BSF / 4 / 256), block, 0, stream>>>(lo2, lo3, lo4, out4, scores);
}